// Round 2
// baseline (239.037 us; speedup 1.0000x reference)
//
#include <hip/hip_runtime.h>
#include <stdint.h>

#define GD    34
#define RS    39          // row stride; 39%32=7 -> only sparse 2/3-way lane aliasing
#define C0N   (38*RS)     // ch0 buffer: 2-row halo top/bottom, 2-col left halo (col center +2)
#define CBN   (36*RS)     // ch1/ch2/x0buf: 1-halo as before
#define NPIX  1156
#define NT    256
#define NB    1024
#define TPR   7           // 5-pixel strips per row (7*5=35 >= 34)
#define TUSED 238         // 34 rows * 7 strips
#define FS    57          // food-halo row stride (init-only path)
#define SCRN  2960        // floats: >= 51*57+52 (conv reads); x0buf[1404] + hist alias this

// wave0 scans the 1024-bin LDS histogram, finds the bin containing rank KK,
// writes sel_bin/sel_rem, zeroes the histogram behind itself.
#define SCAN_PASS(KK) do {                                                         \
    if (wid == 0) {                                                                \
      const int base2 = lane << 4;                                                 \
      int c16[16]; int csum = 0;                                                   \
      _Pragma("unroll")                                                            \
      for (int j = 0; j < 16; ++j) { c16[j] = hist[base2+j]; hist[base2+j] = 0; csum += c16[j]; } \
      int inc = csum;                                                              \
      _Pragma("unroll")                                                            \
      for (int off2 = 1; off2 < 64; off2 <<= 1) { int vv = __shfl_up(inc, off2); if (lane >= off2) inc += vv; } \
      const int excl = inc - csum;                                                 \
      if ((KK) >= excl && (KK) < inc) {                                            \
        int rem = (KK) - excl; int cum = 0;                                        \
        _Pragma("unroll")                                                          \
        for (int j = 0; j < 16; ++j) {                                             \
          if (rem >= cum && rem < cum + c16[j]) { sel_bin = base2 + j; sel_rem = rem - cum; } \
          cum += c16[j];                                                           \
        }                                                                          \
      }                                                                            \
    }                                                                              \
  } while (0)

__global__ __launch_bounds__(NT) __attribute__((amdgpu_waves_per_eu(4, 4)))
void ca_kernel(const float* __restrict__ cell_in,   // [B,4,34,34]
               const float* __restrict__ food_in,   // [B,34,34]
               const float* __restrict__ fc1_w,     // [64,12] (wave-uniform scalar reads)
               const float* __restrict__ fc1_b,     // [64]
               const float* __restrict__ fc2_w,     // [4,64]
               const float* __restrict__ fc2_b,     // [4]
               const float* __restrict__ sk_g,      // [19,19]
               const int*   __restrict__ steps_p,
               float* __restrict__ out)             // [cell | food | tpv | lc]
{
  __shared__ float c0b[C0N];         // ch0, 2-halo (maxpool5 window); halo stays 0
  __shared__ float cbuf1[CBN];       // ch1, 1-halo
  __shared__ float cbuf2[CBN];       // ch2, 1-halo
  __shared__ float scratch[SCRN];    // x0buf[1404]; food-halo (init) and hist[1024] alias it
  __shared__ int   icl[2][4];
  __shared__ int   inzaz[4];
  __shared__ int   sel_bin, sel_rem;
  __shared__ float fsum[4];
  __shared__ int   lcnt[4];

  float* x0buf = scratch;                       // 36x39 halo'd, x_new ch0 (pre-mask/clip)
  int*   hist  = (int*)scratch;                 // aliases x0buf: only live inside radix path,
                                                // self-clears to 0 (the stale-safe value)

  const int tid  = threadIdx.x;
  const int b    = blockIdx.x;
  const int lane = tid & 63;
  const int wid  = tid >> 6;
  const int nsteps = steps_p[0];

  const bool tval = (tid < TUSED);
  const int  trow = tval ? (tid / TPR) : 0;
  const int  c0   = tval ? ((tid % TPR) * 5) : 0;
  const int  nval = tval ? ((c0 <= 29) ? 5 : 4) : 0;   // strip 6 covers cols 30..33
  const int  pb0c = (trow+2)*RS + c0 + 2;              // ch0 own-pixel base (2-halo layout)
  const int  pb1  = (trow+1)*RS + c0 + 1;              // ch1/ch2/x0buf own-pixel base
  const int  p0   = trow*GD + c0;                      // flat pixel base
  const int  wb0  = trow*RS + c0;                      // ch0 5x9 window base: +rr*RS+q, rr 0..4, q 0..8
  const int  wb1  = trow*RS + c0;                      // ch1/2 3x7 window base: +rr*RS+q, rr 0..2, q 0..6

  // ---------------- init ----------------
  for (int idx = tid; idx < C0N;  idx += NT) c0b[idx]   = 0.f;
  for (int idx = tid; idx < CBN;  idx += NT) cbuf1[idx] = 0.f;
  for (int idx = tid; idx < CBN;  idx += NT) cbuf2[idx] = 0.f;
  for (int idx = tid; idx < SCRN; idx += NT) scratch[idx] = 0.f;
  __syncthreads();

  float v3k[5], v1k[5], v2k[5];
  int cnt0 = 0;
#pragma unroll
  for (int j = 0; j < 5; ++j) {
    v3k[j] = 0.f; v1k[j] = 0.f; v2k[j] = 0.f;
    if (j < nval) {
      int p = p0 + j;
      const float* gi = cell_in + (size_t)b*4*NPIX + p;
      float v0 = gi[0], v1 = gi[NPIX], v2 = gi[2*NPIX], v3 = gi[3*NPIX];
      c0b[pb0c+j] = v0; cbuf1[pb1+j] = v1; cbuf2[pb1+j] = v2;
      v3k[j] = v3;
      cnt0 += (v0 > 0.8f) ? 1 : 0;
      scratch[(trow+9)*FS + (c0+j+9)] = food_in[(size_t)b*NPIX + p];  // 9-halo, stride FS
    }
  }
#pragma unroll
  for (int off = 32; off; off >>= 1) cnt0 += __shfl_down(cnt0, off);
  if (lane == 0) icl[0][wid] = cnt0;
  __syncthreads();

  // scent: 19x19 gaussian conv, once. Row-register reuse: 23 loads/row feed all 5 pixels
  // (accumulation order per pixel identical to naive dr-outer/dc-inner -> bit-exact).
  float scent[5] = {0.f, 0.f, 0.f, 0.f, 0.f};
  for (int dr = 0; dr < 19; ++dr) {
    const float* frow = scratch + (trow+dr)*FS + c0;
    float f[23];
#pragma unroll
    for (int q = 0; q < 23; ++q) f[q] = frow[q];
    const float* krow = sk_g + dr*19;
#pragma unroll
    for (int dc = 0; dc < 19; ++dc) {
      const float kv = krow[dc];
      scent[0] = fmaf(f[dc+0], kv, scent[0]);
      scent[1] = fmaf(f[dc+1], kv, scent[1]);
      scent[2] = fmaf(f[dc+2], kv, scent[2]);
      scent[3] = fmaf(f[dc+3], kv, scent[3]);
      scent[4] = fmaf(f[dc+4], kv, scent[4]);
    }
  }
  __syncthreads();
  for (int idx = tid; idx < SCRN; idx += NT) scratch[idx] = 0.f;  // x0buf halo must be 0
  __syncthreads();
#pragma unroll
  for (int j = 0; j < 5; ++j) if (j < nval) x0buf[pb1+j] = scent[j];
  __syncthreads();
  // ch3 := scent every step -> its sobels are step-invariant
  float sxs[5], sys[5];
#pragma unroll
  for (int j = 0; j < 5; ++j) {
    const int bb = (j < nval) ? (pb1 + j) : pb1;
    float t00=x0buf[bb-RS-1], t01=x0buf[bb-RS], t02=x0buf[bb-RS+1];
    float t10=x0buf[bb-1],                      t12=x0buf[bb+1];
    float t20=x0buf[bb+RS-1], t21=x0buf[bb+RS], t22=x0buf[bb+RS+1];
    sxs[j] = ((t02 - t00) + 2.f*(t12 - t10) + (t22 - t20)) * 0.125f;
    sys[j] = ((t20 - t00) + 2.f*(t21 - t01) + (t22 - t02)) * 0.125f;
  }
  // x0buf content is stale-safe (only premask-false pixels ever read stale entries)

  const float b2r0 = fc2_b[0], b2r1 = fc2_b[1], b2r2 = fc2_b[2], b2r3 = fc2_b[3];

  // ---------------- steps ----------------
  for (int s = 0; s < nsteps; ++s) {
    __syncthreads();                       // top: prev writeback/radix -> this step's reads
    // --- P1: one 5x9 ch0 window (row-major, pairable reads) yields:
    //     pm  = maxpool3(ch0)>0.1           (middle 3x3, exact fmax order preserved)
    //     am  = maxpool5(ch0)>0.1 == OR_3x3(pm)   (exact boolean identity)
    //     r0/r1/r2 register rows for y0/y4/y8 (no LDS in MLP phase)
    float a0[9], a4[9], m3[9], r0[9], r1[9], r2[9];
#pragma unroll
    for (int q = 0; q < 9; ++q) a0[q] = c0b[wb0 + q];
#pragma unroll
    for (int q = 0; q < 9; ++q) { r0[q] = c0b[wb0 + RS + q];   m3[q] = r0[q]; }
#pragma unroll
    for (int q = 0; q < 9; ++q) { r1[q] = c0b[wb0 + 2*RS + q]; m3[q] = fmaxf(m3[q], r1[q]); }
#pragma unroll
    for (int q = 0; q < 9; ++q) { r2[q] = c0b[wb0 + 3*RS + q]; m3[q] = fmaxf(m3[q], r2[q]); }
#pragma unroll
    for (int q = 0; q < 9; ++q) a4[q] = c0b[wb0 + 4*RS + q];
    float m5[9];
#pragma unroll
    for (int q = 0; q < 9; ++q) m5[q] = fmaxf(fmaxf(a0[q], m3[q]), a4[q]);
    unsigned pm = 0, am = 0;
#pragma unroll
    for (int j = 0; j < 5; ++j) {
      if (j < nval) {
        if (fmaxf(fmaxf(m3[j+1], m3[j+2]), m3[j+3]) > 0.1f) pm |= (1u << j);
        float mm5 = fmaxf(fmaxf(fmaxf(fmaxf(m5[j], m5[j+1]), m5[j+2]), m5[j+3]), m5[j+4]);
        if (mm5 > 0.1f) am |= (1u << j);
      }
    }
    // y0/y4/y8 from the register window (pixel j -> window cols j+1..j+3)
    float y0a[5], y4a[5], y8a[5];
#pragma unroll
    for (int j = 0; j < 5; ++j) {
      y0a[j] = r1[j+2];
      y4a[j] = ((r0[j+3] - r0[j+1]) + 2.f*(r1[j+3] - r1[j+1]) + (r2[j+3] - r2[j+1])) * 0.125f;
      y8a[j] = ((r2[j+1] - r0[j+1]) + 2.f*(r2[j+2] - r0[j+2]) + (r2[j+3] - r0[j+3])) * 0.125f;
    }
    // --- P2 + MLP: only if some pixel in this wave is inside the premask dilation ---
    if (__any(am != 0u)) {
      float y1a[5], y5a[5], y9a[5], y2a[5], y6a[5], y10a[5];
      {
        float s0[7], s1[7], s2[7];
#pragma unroll
        for (int q = 0; q < 7; ++q) s0[q] = cbuf1[wb1 + q];
#pragma unroll
        for (int q = 0; q < 7; ++q) s1[q] = cbuf1[wb1 + RS + q];
#pragma unroll
        for (int q = 0; q < 7; ++q) s2[q] = cbuf1[wb1 + 2*RS + q];
#pragma unroll
        for (int j = 0; j < 5; ++j) {
          y1a[j] = s1[j+1];
          y5a[j] = ((s0[j+2] - s0[j]) + 2.f*(s1[j+2] - s1[j]) + (s2[j+2] - s2[j])) * 0.125f;
          y9a[j] = ((s2[j]   - s0[j]) + 2.f*(s2[j+1] - s0[j+1]) + (s2[j+2] - s0[j+2])) * 0.125f;
        }
      }
      {
        float s0[7], s1[7], s2[7];
#pragma unroll
        for (int q = 0; q < 7; ++q) s0[q] = cbuf2[wb1 + q];
#pragma unroll
        for (int q = 0; q < 7; ++q) s1[q] = cbuf2[wb1 + RS + q];
#pragma unroll
        for (int q = 0; q < 7; ++q) s2[q] = cbuf2[wb1 + 2*RS + q];
#pragma unroll
        for (int j = 0; j < 5; ++j) {
          y2a[j]  = s1[j+1];
          y6a[j]  = ((s0[j+2] - s0[j]) + 2.f*(s1[j+2] - s1[j]) + (s2[j+2] - s2[j])) * 0.125f;
          y10a[j] = ((s2[j]   - s0[j]) + 2.f*(s2[j+1] - s0[j+1]) + (s2[j+2] - s0[j+2])) * 0.125f;
        }
      }
#pragma unroll
      for (int j = 0; j < 5; ++j) {
        int acti = (j < nval) ? (int)((am >> j) & 1u) : 0;
        if (__any(acti)) {
          const float y0 = y0a[j], y1 = y1a[j], y2 = y2a[j],  y3  = scent[j];
          const float y4 = y4a[j], y5 = y5a[j], y6 = y6a[j],  y7  = sxs[j];
          const float y8 = y8a[j], y9 = y9a[j], y10 = y10a[j], y11 = sys[j];
          float u0 = b2r0, u1 = b2r1, u2 = b2r2, u3 = b2r3;
          for (int o = 0; o < 64; ++o) {   // weights: wave-uniform scalar loads (K$)
            const float* wr = fc1_w + o*12;
            float t = fc1_b[o];
            t = fmaf(y0, wr[0], t);  t = fmaf(y1, wr[1], t);
            t = fmaf(y2, wr[2], t);  t = fmaf(y3, wr[3], t);
            t = fmaf(y4, wr[4], t);  t = fmaf(y5, wr[5], t);
            t = fmaf(y6, wr[6], t);  t = fmaf(y7, wr[7], t);
            t = fmaf(y8, wr[8], t);  t = fmaf(y9, wr[9], t);
            t = fmaf(y10, wr[10], t); t = fmaf(y11, wr[11], t);
            t = fmaxf(t, 0.f);
            u0 = fmaf(t, fc2_w[o],     u0);
            u1 = fmaf(t, fc2_w[64+o],  u1);
            u2 = fmaf(t, fc2_w[128+o], u2);
            u3 = fmaf(t, fc2_w[192+o], u3);
          }
          v3k[j] = y3 + u3;                // x_new ch3, pre-clip, held in-place
          if (j < nval) {
            x0buf[pb1+j] = y0 + u0;        // x_new ch0, pre-mask/clip (for postmask pool)
            v1k[j]       = y1 + u1;        // x_new ch1/ch2 stay in registers
            v2k[j]       = y2 + u2;
          }
        }
      }
    }
    __syncthreads();                       // sync2: x0buf writes -> C reads
    // --- C: postmask (only where premask), masks+clips, counts ---
    unsigned pq = 0;
    float midv[5];
#pragma unroll
    for (int j = 0; j < 5; ++j) midv[j] = 0.f;
    if (pm) {
      float dm[7];
#pragma unroll
      for (int jc = 0; jc < 7; ++jc) {
        dm[jc] = 0.f;
        if (jc < nval + 2) {
          const int a = pb1 - 1 + jc;
          float u = x0buf[a-RS], m = x0buf[a], d = x0buf[a+RS];
          dm[jc] = fmaxf(fmaxf(u, m), d);
          if (jc >= 1 && jc <= 5) midv[jc-1] = m;   // own x_new ch0 values
        }
      }
#pragma unroll
      for (int j = 0; j < 5; ++j)
        if (fmaxf(fmaxf(dm[j], dm[j+1]), dm[j+2]) > 0.1f) pq |= (1u << j);
    }
    int packed = 0;                        // nz | az<<16
    float v0s[5];
#pragma unroll
    for (int j = 0; j < 5; ++j) {
      v0s[j] = 0.f;
      if (j < nval) {
        bool alive = ((pm >> j) & 1u) && ((pq >> j) & 1u);
        float v0 = 0.f, v1 = 0.f, v2 = 0.f, v3 = 0.f;
        if (alive) {
          v0 = fminf(fmaxf(midv[j],   0.f),  1.f);
          v1 = fminf(fmaxf(v1k[j],  -10.f), 10.f);
          v2 = fminf(fmaxf(v2k[j],  -10.f), 10.f);
          v3 = fminf(fmaxf(v3k[j],  -10.f), 10.f);
        }
        cbuf1[pb1+j] = v1; cbuf2[pb1+j] = v2; v3k[j] = v3;
        v0s[j] = v0;
        int zer = (v0 == 0.f) ? 1 : 0;
        int azf = (zer && v1 == 0.f && v2 == 0.f && v3 == 0.f) ? 1 : 0;
        packed += zer + (azf << 16);
      }
    }
#pragma unroll
    for (int off = 32; off; off >>= 1) packed += __shfl_down(packed, off);
    if (lane == 0) inzaz[wid] = packed;
    __syncthreads();                       // sync3 (x0buf fully consumed after this)
    const int t01 = inzaz[0]+inzaz[1]+inzaz[2]+inzaz[3];
    const int nz = t01 & 0xffff, az = t01 >> 16;
    const int cl = icl[s&1][0]+icl[s&1][1]+icl[s&1][2]+icl[s&1][3];
    const int k  = (cl < NPIX) ? cl : (NPIX-1);
    float kth = 0.f;
    if (k >= nz) {                         // rare: k-th value nonzero -> 3-pass radix select
      hist[tid] = 0; hist[tid+256] = 0; hist[tid+512] = 0; hist[tid+768] = 0;  // hist aliases x0buf
      __syncthreads();
      const int k2 = k - nz;
#pragma unroll
      for (int j = 0; j < 5; ++j) {
        unsigned u = __float_as_uint(v0s[j]);
        if (j < nval && u != 0u) atomicAdd(&hist[u >> 20], 1);
      }
      __syncthreads();
      SCAN_PASS(k2);
      __syncthreads();
      const int bin1 = sel_bin; const int kr2 = sel_rem;
#pragma unroll
      for (int j = 0; j < 5; ++j) {
        unsigned u = __float_as_uint(v0s[j]);
        if (j < nval && u != 0u && (u >> 20) == (unsigned)bin1)
          atomicAdd(&hist[(u >> 10) & 1023u], 1);
      }
      __syncthreads();
      SCAN_PASS(kr2);
      __syncthreads();
      const int bin2 = sel_bin; const int kr3 = sel_rem;
      const unsigned pref2 = (((unsigned)bin1) << 10) | (unsigned)bin2;
#pragma unroll
      for (int j = 0; j < 5; ++j) {
        unsigned u = __float_as_uint(v0s[j]);
        if (j < nval && u != 0u && (u >> 10) == pref2)
          atomicAdd(&hist[u & 1023u], 1);
      }
      __syncthreads();
      SCAN_PASS(kr3);
      __syncthreads();
      kth = __uint_as_float((((unsigned)bin1) << 20) | (((unsigned)bin2) << 10) | (unsigned)sel_bin);
      // SCAN_PASS self-clears hist -> x0buf region left zeroed (stale-safe)
    }
    // --- writeback + next step's living count ---
    int cnt = 0;
#pragma unroll
    for (int j = 0; j < 5; ++j) {
      if (j < nval) {
        float w0 = (v0s[j] > kth) ? v0s[j] : 0.f;
        c0b[pb0c+j] = w0;
        cnt += (w0 > 0.8f) ? 1 : 0;
      }
    }
#pragma unroll
    for (int off = 32; off; off >>= 1) cnt += __shfl_down(cnt, off);
    if (lane == 0) icl[(s+1)&1][wid] = cnt;
    if (az == NPIX) break;                 // all-zero state is an exact fixed point
  }

  // ---------------- epilogue ----------------
  const size_t CELL_N = (size_t)4*NPIX*NB;
  const size_t FOOD_N = (size_t)NPIX*NB;
  float tp = 0.f; int lcv = 0;
#pragma unroll
  for (int j = 0; j < 5; ++j) {
    if (j < nval) {
      const int p = p0 + j;
      float c0v = c0b[pb0c+j], c1 = cbuf1[pb1+j], c2 = cbuf2[pb1+j]; // self-written
      size_t go = (size_t)b*4*NPIX + p;
      out[go]          = c0v;
      out[go +   NPIX] = c1;
      out[go + 2*NPIX] = c2;
      out[go + 3*NPIX] = v3k[j];
      out[CELL_N + (size_t)b*NPIX + p] = food_in[(size_t)b*NPIX + p];
      tp += c0v;
      lcv += (c0v > 0.1f) ? 1 : 0;
    }
  }
#pragma unroll
  for (int off = 32; off; off >>= 1) { tp += __shfl_down(tp, off); lcv += __shfl_down(lcv, off); }
  if (lane == 0) { fsum[wid] = tp; lcnt[wid] = lcv; }
  __syncthreads();
  if (tid == 0) {
    out[CELL_N + FOOD_N + b]      = fsum[0]+fsum[1]+fsum[2]+fsum[3];
    out[CELL_N + FOOD_N + NB + b] = (float)(lcnt[0]+lcnt[1]+lcnt[2]+lcnt[3]);
  }
}

extern "C" void kernel_launch(void* const* d_in, const int* in_sizes, int n_in,
                              void* d_out, int out_size, void* d_ws, size_t ws_size,
                              hipStream_t stream) {
  const float* cell  = (const float*)d_in[0];
  const float* food  = (const float*)d_in[1];
  const float* fc1w  = (const float*)d_in[2];
  const float* fc1b  = (const float*)d_in[3];
  const float* fc2w  = (const float*)d_in[4];
  const float* fc2b  = (const float*)d_in[5];
  const float* sk    = (const float*)d_in[6];
  const int*   steps = (const int*)d_in[7];
  float* out = (float*)d_out;
  ca_kernel<<<NB, NT, 0, stream>>>(cell, food, fc1w, fc1b, fc2w, fc2b, sk, steps, out);
}

// Round 3
// 236.713 us; speedup vs baseline: 1.0098x; 1.0098x over previous
//
#include <hip/hip_runtime.h>
#include <stdint.h>

#define GD    34
#define RS    39          // row stride; 39%32=7 -> only sparse 2/3-way lane aliasing
#define C0N   (38*RS)     // ch0 buffer: 2-halo all around (maxpool5 window), 38x39
#define CBN   (36*RS)     // ch1/ch2/x0buf: 1-halo, 36x39
#define NPIX  1156
#define NT    256
#define NB    1024
#define TPR   7           // 5-pixel strips per row (7*5=35 >= 34)
#define TUSED 238         // 34 rows * 7 strips
#define FS    57          // food-halo row stride (init-only path)
#define SCRN  2960        // floats: >= 51*57+52 (conv reads); x0buf[1404] + hist[1024] alias this

// wave0 scans the 1024-bin LDS histogram, finds the bin containing rank KK,
// writes sel_bin/sel_rem, zeroes the histogram behind itself.
#define SCAN_PASS(KK) do {                                                         \
    if (wid == 0) {                                                                \
      const int base2 = lane << 4;                                                 \
      int c16[16]; int csum = 0;                                                   \
      _Pragma("unroll")                                                            \
      for (int j = 0; j < 16; ++j) { c16[j] = hist[base2+j]; hist[base2+j] = 0; csum += c16[j]; } \
      int inc = csum;                                                              \
      _Pragma("unroll")                                                            \
      for (int off2 = 1; off2 < 64; off2 <<= 1) { int vv = __shfl_up(inc, off2); if (lane >= off2) inc += vv; } \
      const int excl = inc - csum;                                                 \
      if ((KK) >= excl && (KK) < inc) {                                            \
        int rem = (KK) - excl; int cum = 0;                                        \
        _Pragma("unroll")                                                          \
        for (int j = 0; j < 16; ++j) {                                             \
          if (rem >= cum && rem < cum + c16[j]) { sel_bin = base2 + j; sel_rem = rem - cum; } \
          cum += c16[j];                                                           \
        }                                                                          \
      }                                                                            \
    }                                                                              \
  } while (0)

__global__ __launch_bounds__(NT) __attribute__((amdgpu_waves_per_eu(4, 4)))
void ca_kernel(const float* __restrict__ cell_in,   // [B,4,34,34]
               const float* __restrict__ food_in,   // [B,34,34]
               const float* __restrict__ fc1_w,     // [64,12] (wave-uniform scalar reads)
               const float* __restrict__ fc1_b,     // [64]
               const float* __restrict__ fc2_w,     // [4,64]
               const float* __restrict__ fc2_b,     // [4]
               const float* __restrict__ sk_g,      // [19,19]
               const int*   __restrict__ steps_p,
               float* __restrict__ out)             // [cell | food | tpv | lc]
{
  __shared__ float c0b[C0N];         // ch0, 2-halo; halo stays 0 (exact: 0 < 0.1 threshold)
  __shared__ float cbuf1[CBN];       // ch1, 1-halo
  __shared__ float cbuf2[CBN];       // ch2, 1-halo
  __shared__ float scratch[SCRN];    // x0buf[1404]; food-halo (init) and hist[1024] alias it
  __shared__ int   icl[2][4];
  __shared__ int   inzaz[4];
  __shared__ int   sel_bin, sel_rem;
  __shared__ float fsum[4];
  __shared__ int   lcnt[4];

  float* x0buf = scratch;                       // 36x39 halo'd, x_new ch0 (pre-mask/clip)
  int*   hist  = (int*)scratch;                 // aliases x0buf: only live inside radix path,
                                                // self-clears to 0 (the stale-safe value)

  const int tid  = threadIdx.x;
  const int b    = blockIdx.x;
  const int lane = tid & 63;
  const int wid  = tid >> 6;
  const int nsteps = steps_p[0];

  const bool tval = (tid < TUSED);
  const int  trow = tval ? (tid / TPR) : 0;
  const int  c0   = tval ? ((tid % TPR) * 5) : 0;
  const int  nval = tval ? ((c0 <= 29) ? 5 : 4) : 0;   // strip 6 covers cols 30..33
  const int  pb0c = (trow+2)*RS + c0 + 2;              // ch0 own-pixel base (2-halo layout)
  const int  pb1  = (trow+1)*RS + c0 + 1;              // ch1/ch2/x0buf own-pixel base
  const int  p0   = trow*GD + c0;                      // flat pixel base
  const int  wb0  = trow*RS + c0;                      // ch0 5x9 window base: +rr*RS+q, rr 0..4, q 0..8

  // ---------------- init ----------------
  for (int idx = tid; idx < C0N;  idx += NT) c0b[idx]   = 0.f;
  for (int idx = tid; idx < CBN;  idx += NT) cbuf1[idx] = 0.f;
  for (int idx = tid; idx < CBN;  idx += NT) cbuf2[idx] = 0.f;
  for (int idx = tid; idx < SCRN; idx += NT) scratch[idx] = 0.f;
  __syncthreads();

  float v3k[5], v1k[5], v2k[5];
  int cnt0 = 0;
#pragma unroll
  for (int j = 0; j < 5; ++j) {
    v3k[j] = 0.f; v1k[j] = 0.f; v2k[j] = 0.f;
    if (j < nval) {
      int p = p0 + j;
      const float* gi = cell_in + (size_t)b*4*NPIX + p;
      float v0 = gi[0], v1 = gi[NPIX], v2 = gi[2*NPIX], v3 = gi[3*NPIX];
      c0b[pb0c+j] = v0; cbuf1[pb1+j] = v1; cbuf2[pb1+j] = v2;
      v3k[j] = v3;
      cnt0 += (v0 > 0.8f) ? 1 : 0;
      scratch[(trow+9)*FS + (c0+j+9)] = food_in[(size_t)b*NPIX + p];  // 9-halo, stride FS
    }
  }
#pragma unroll
  for (int off = 32; off; off >>= 1) cnt0 += __shfl_down(cnt0, off);
  if (lane == 0) icl[0][wid] = cnt0;
  __syncthreads();

  // scent: 19x19 gaussian conv, once. Row-register reuse: 23 loads/row feed all 5 pixels
  // (accumulation order per pixel identical to naive dr-outer/dc-inner -> bit-exact).
  float scent[5] = {0.f, 0.f, 0.f, 0.f, 0.f};
  for (int dr = 0; dr < 19; ++dr) {
    const float* frow = scratch + (trow+dr)*FS + c0;
    float f[23];
#pragma unroll
    for (int q = 0; q < 23; ++q) f[q] = frow[q];
    const float* krow = sk_g + dr*19;
#pragma unroll
    for (int dc = 0; dc < 19; ++dc) {
      const float kv = krow[dc];
      scent[0] = fmaf(f[dc+0], kv, scent[0]);
      scent[1] = fmaf(f[dc+1], kv, scent[1]);
      scent[2] = fmaf(f[dc+2], kv, scent[2]);
      scent[3] = fmaf(f[dc+3], kv, scent[3]);
      scent[4] = fmaf(f[dc+4], kv, scent[4]);
    }
  }
  __syncthreads();
  for (int idx = tid; idx < SCRN; idx += NT) scratch[idx] = 0.f;  // x0buf halo must be 0
  __syncthreads();
#pragma unroll
  for (int j = 0; j < 5; ++j) if (j < nval) x0buf[pb1+j] = scent[j];
  __syncthreads();
  // ch3 := scent every step -> its sobels are step-invariant
  float sxs[5], sys[5];
#pragma unroll
  for (int j = 0; j < 5; ++j) {
    const int bb = (j < nval) ? (pb1 + j) : pb1;
    float t00=x0buf[bb-RS-1], t01=x0buf[bb-RS], t02=x0buf[bb-RS+1];
    float t10=x0buf[bb-1],                      t12=x0buf[bb+1];
    float t20=x0buf[bb+RS-1], t21=x0buf[bb+RS], t22=x0buf[bb+RS+1];
    sxs[j] = ((t02 - t00) + 2.f*(t12 - t10) + (t22 - t20)) * 0.125f;
    sys[j] = ((t20 - t00) + 2.f*(t21 - t01) + (t22 - t02)) * 0.125f;
  }
  // x0buf content is stale-safe (only premask-false pixels ever read stale entries)

  const float b2r0 = fc2_b[0], b2r1 = fc2_b[1], b2r2 = fc2_b[2], b2r3 = fc2_b[3];

  // ---------------- steps ----------------
  for (int s = 0; s < nsteps; ++s) {
    __syncthreads();                       // top: prev writeback/radix -> this step's reads
    // --- P1: 5x9 ch0 window, register-lean:
    //   rows 1..3: keep only cols 1..7 (sobel reuse) in r0/r1/r2; edge cols fold into m3.
    //   rows 0,4: pure transients folded into m5.
    //   pm = maxpool3(ch0)>0.1 ; am = maxpool5(ch0)>0.1 == OR_3x3(pm) (exact identity;
    //   fmax order freedom: max is associative/commutative, inputs are clipped non-NaN).
    float r0[7], r1[7], r2[7], m3[9], m5[9];
    {
      m3[0] = c0b[wb0 + RS];
#pragma unroll
      for (int i = 0; i < 7; ++i) { r0[i] = c0b[wb0 + RS + 1 + i]; m3[i+1] = r0[i]; }
      m3[8] = c0b[wb0 + RS + 8];
      m3[0] = fmaxf(m3[0], c0b[wb0 + 2*RS]);
#pragma unroll
      for (int i = 0; i < 7; ++i) { r1[i] = c0b[wb0 + 2*RS + 1 + i]; m3[i+1] = fmaxf(m3[i+1], r1[i]); }
      m3[8] = fmaxf(m3[8], c0b[wb0 + 2*RS + 8]);
      m3[0] = fmaxf(m3[0], c0b[wb0 + 3*RS]);
#pragma unroll
      for (int i = 0; i < 7; ++i) { r2[i] = c0b[wb0 + 3*RS + 1 + i]; m3[i+1] = fmaxf(m3[i+1], r2[i]); }
      m3[8] = fmaxf(m3[8], c0b[wb0 + 3*RS + 8]);
#pragma unroll
      for (int q = 0; q < 9; ++q) m5[q] = fmaxf(fmaxf(c0b[wb0 + q], m3[q]), c0b[wb0 + 4*RS + q]);
    }
    unsigned pm = 0, am = 0;
#pragma unroll
    for (int j = 0; j < 5; ++j) {
      if (j < nval) {
        if (fmaxf(fmaxf(m3[j+1], m3[j+2]), m3[j+3]) > 0.1f) pm |= (1u << j);
        float mm5 = fmaxf(fmaxf(fmaxf(fmaxf(m5[j], m5[j+1]), m5[j+2]), m5[j+3]), m5[j+4]);
        if (mm5 > 0.1f) am |= (1u << j);
      }
    }
    // --- MLP: per-pixel, gated; ch0 from registers, ch1/ch2 via gated per-pixel LDS reads ---
#pragma unroll
    for (int j = 0; j < 5; ++j) {
      int acti = (j < nval) ? (int)((am >> j) & 1u) : 0;
      if (__any(acti)) {
        const int bb = pb1 + j;            // idle threads: pb1 interior, results discarded
        // ch0 from r-window: pixel j -> r indices j..j+2 (window cols j+1..j+3)
        const float y0 = r1[j+1];
        const float y4 = ((r0[j+2] - r0[j]) + 2.f*(r1[j+2] - r1[j]) + (r2[j+2] - r2[j])) * 0.125f;
        const float y8 = ((r2[j] - r0[j]) + 2.f*(r2[j+1] - r0[j+1]) + (r2[j+2] - r0[j+2])) * 0.125f;
        float y1, y5, y9, y2, y6, y10;
        {
          const float* cb = cbuf1;
          float t00=cb[bb-RS-1], t01=cb[bb-RS], t02=cb[bb-RS+1];
          float t10=cb[bb-1],    t11=cb[bb],    t12=cb[bb+1];
          float t20=cb[bb+RS-1], t21=cb[bb+RS], t22=cb[bb+RS+1];
          y1 = t11;
          y5 = ((t02 - t00) + 2.f*(t12 - t10) + (t22 - t20)) * 0.125f;
          y9 = ((t20 - t00) + 2.f*(t21 - t01) + (t22 - t02)) * 0.125f;
        }
        {
          const float* cb = cbuf2;
          float t00=cb[bb-RS-1], t01=cb[bb-RS], t02=cb[bb-RS+1];
          float t10=cb[bb-1],    t11=cb[bb],    t12=cb[bb+1];
          float t20=cb[bb+RS-1], t21=cb[bb+RS], t22=cb[bb+RS+1];
          y2 = t11;
          y6 = ((t02 - t00) + 2.f*(t12 - t10) + (t22 - t20)) * 0.125f;
          y10= ((t20 - t00) + 2.f*(t21 - t01) + (t22 - t02)) * 0.125f;
        }
        const float y3 = scent[j], y7 = sxs[j], y11 = sys[j];
        float u0 = b2r0, u1 = b2r1, u2 = b2r2, u3 = b2r3;
        for (int o = 0; o < 64; ++o) {     // weights: wave-uniform scalar loads (K$)
          const float* wr = fc1_w + o*12;
          float t = fc1_b[o];
          t = fmaf(y0, wr[0], t);  t = fmaf(y1, wr[1], t);
          t = fmaf(y2, wr[2], t);  t = fmaf(y3, wr[3], t);
          t = fmaf(y4, wr[4], t);  t = fmaf(y5, wr[5], t);
          t = fmaf(y6, wr[6], t);  t = fmaf(y7, wr[7], t);
          t = fmaf(y8, wr[8], t);  t = fmaf(y9, wr[9], t);
          t = fmaf(y10, wr[10], t); t = fmaf(y11, wr[11], t);
          t = fmaxf(t, 0.f);
          u0 = fmaf(t, fc2_w[o],     u0);
          u1 = fmaf(t, fc2_w[64+o],  u1);
          u2 = fmaf(t, fc2_w[128+o], u2);
          u3 = fmaf(t, fc2_w[192+o], u3);
        }
        v3k[j] = y3 + u3;                  // x_new ch3, pre-clip, held in-place
        if (j < nval) {
          x0buf[bb]  = y0 + u0;            // x_new ch0, pre-mask/clip (for postmask pool)
          v1k[j]     = y1 + u1;            // x_new ch1/ch2 stay in registers
          v2k[j]     = y2 + u2;
        }
      }
    }
    __syncthreads();                       // sync2: x0buf writes -> C reads
    // --- C: postmask (only where premask), masks+clips, counts ---
    unsigned pq = 0;
    float midv[5];
#pragma unroll
    for (int j = 0; j < 5; ++j) midv[j] = 0.f;
    if (pm) {
      float dm[7];
#pragma unroll
      for (int jc = 0; jc < 7; ++jc) {
        dm[jc] = 0.f;
        if (jc < nval + 2) {
          const int a = pb1 - 1 + jc;
          float u = x0buf[a-RS], m = x0buf[a], d = x0buf[a+RS];
          dm[jc] = fmaxf(fmaxf(u, m), d);
          if (jc >= 1 && jc <= 5) midv[jc-1] = m;   // own x_new ch0 values
        }
      }
#pragma unroll
      for (int j = 0; j < 5; ++j)
        if (fmaxf(fmaxf(dm[j], dm[j+1]), dm[j+2]) > 0.1f) pq |= (1u << j);
    }
    int packed = 0;                        // nz | az<<16
    float v0s[5];
#pragma unroll
    for (int j = 0; j < 5; ++j) {
      v0s[j] = 0.f;
      if (j < nval) {
        bool alive = ((pm >> j) & 1u) && ((pq >> j) & 1u);
        float v0 = 0.f, v1 = 0.f, v2 = 0.f, v3 = 0.f;
        if (alive) {
          v0 = fminf(fmaxf(midv[j],   0.f),  1.f);
          v1 = fminf(fmaxf(v1k[j],  -10.f), 10.f);
          v2 = fminf(fmaxf(v2k[j],  -10.f), 10.f);
          v3 = fminf(fmaxf(v3k[j],  -10.f), 10.f);
        }
        cbuf1[pb1+j] = v1; cbuf2[pb1+j] = v2; v3k[j] = v3;
        v0s[j] = v0;
        int zer = (v0 == 0.f) ? 1 : 0;
        int azf = (zer && v1 == 0.f && v2 == 0.f && v3 == 0.f) ? 1 : 0;
        packed += zer + (azf << 16);
      }
    }
#pragma unroll
    for (int off = 32; off; off >>= 1) packed += __shfl_down(packed, off);
    if (lane == 0) inzaz[wid] = packed;
    __syncthreads();                       // sync3 (x0buf fully consumed after this)
    const int t01 = inzaz[0]+inzaz[1]+inzaz[2]+inzaz[3];
    const int nz = t01 & 0xffff, az = t01 >> 16;
    const int cl = icl[s&1][0]+icl[s&1][1]+icl[s&1][2]+icl[s&1][3];
    const int k  = (cl < NPIX) ? cl : (NPIX-1);
    float kth = 0.f;
    if (k >= nz) {                         // rare: k-th value nonzero -> 3-pass radix select
      hist[tid] = 0; hist[tid+256] = 0; hist[tid+512] = 0; hist[tid+768] = 0;  // hist aliases x0buf
      __syncthreads();
      const int k2 = k - nz;
#pragma unroll
      for (int j = 0; j < 5; ++j) {
        unsigned u = __float_as_uint(v0s[j]);
        if (j < nval && u != 0u) atomicAdd(&hist[u >> 20], 1);
      }
      __syncthreads();
      SCAN_PASS(k2);
      __syncthreads();
      const int bin1 = sel_bin; const int kr2 = sel_rem;
#pragma unroll
      for (int j = 0; j < 5; ++j) {
        unsigned u = __float_as_uint(v0s[j]);
        if (j < nval && u != 0u && (u >> 20) == (unsigned)bin1)
          atomicAdd(&hist[(u >> 10) & 1023u], 1);
      }
      __syncthreads();
      SCAN_PASS(kr2);
      __syncthreads();
      const int bin2 = sel_bin; const int kr3 = sel_rem;
      const unsigned pref2 = (((unsigned)bin1) << 10) | (unsigned)bin2;
#pragma unroll
      for (int j = 0; j < 5; ++j) {
        unsigned u = __float_as_uint(v0s[j]);
        if (j < nval && u != 0u && (u >> 10) == pref2)
          atomicAdd(&hist[u & 1023u], 1);
      }
      __syncthreads();
      SCAN_PASS(kr3);
      __syncthreads();
      kth = __uint_as_float((((unsigned)bin1) << 20) | (((unsigned)bin2) << 10) | (unsigned)sel_bin);
      // SCAN_PASS self-clears hist -> x0buf region left zeroed (stale-safe)
    }
    // --- writeback + next step's living count ---
    int cnt = 0;
#pragma unroll
    for (int j = 0; j < 5; ++j) {
      if (j < nval) {
        float w0 = (v0s[j] > kth) ? v0s[j] : 0.f;
        c0b[pb0c+j] = w0;
        cnt += (w0 > 0.8f) ? 1 : 0;
      }
    }
#pragma unroll
    for (int off = 32; off; off >>= 1) cnt += __shfl_down(cnt, off);
    if (lane == 0) icl[(s+1)&1][wid] = cnt;
    if (az == NPIX) break;                 // all-zero state is an exact fixed point
  }

  // ---------------- epilogue ----------------
  const size_t CELL_N = (size_t)4*NPIX*NB;
  const size_t FOOD_N = (size_t)NPIX*NB;
  float tp = 0.f; int lcv = 0;
#pragma unroll
  for (int j = 0; j < 5; ++j) {
    if (j < nval) {
      const int p = p0 + j;
      float c0v = c0b[pb0c+j], c1 = cbuf1[pb1+j], c2 = cbuf2[pb1+j]; // self-written
      size_t go = (size_t)b*4*NPIX + p;
      out[go]          = c0v;
      out[go +   NPIX] = c1;
      out[go + 2*NPIX] = c2;
      out[go + 3*NPIX] = v3k[j];
      out[CELL_N + (size_t)b*NPIX + p] = food_in[(size_t)b*NPIX + p];
      tp += c0v;
      lcv += (c0v > 0.1f) ? 1 : 0;
    }
  }
#pragma unroll
  for (int off = 32; off; off >>= 1) { tp += __shfl_down(tp, off); lcv += __shfl_down(lcv, off); }
  if (lane == 0) { fsum[wid] = tp; lcnt[wid] = lcv; }
  __syncthreads();
  if (tid == 0) {
    out[CELL_N + FOOD_N + b]      = fsum[0]+fsum[1]+fsum[2]+fsum[3];
    out[CELL_N + FOOD_N + NB + b] = (float)(lcnt[0]+lcnt[1]+lcnt[2]+lcnt[3]);
  }
}

extern "C" void kernel_launch(void* const* d_in, const int* in_sizes, int n_in,
                              void* d_out, int out_size, void* d_ws, size_t ws_size,
                              hipStream_t stream) {
  const float* cell  = (const float*)d_in[0];
  const float* food  = (const float*)d_in[1];
  const float* fc1w  = (const float*)d_in[2];
  const float* fc1b  = (const float*)d_in[3];
  const float* fc2w  = (const float*)d_in[4];
  const float* fc2b  = (const float*)d_in[5];
  const float* sk    = (const float*)d_in[6];
  const int*   steps = (const int*)d_in[7];
  float* out = (float*)d_out;
  ca_kernel<<<NB, NT, 0, stream>>>(cell, food, fc1w, fc1b, fc2w, fc2b, sk, steps, out);
}